// Round 5
// baseline (1227.235 us; speedup 1.0000x reference)
//
#include <hip/hip_runtime.h>
#include <math.h>

#define NN 30000
#define EE 480000
#define AVG_D_LOG 2.833f
#define EPSF 1e-5f
#define ATP 772            // padded LDS row: 768+4 (16B-aligned, conflict-light)

__device__ __forceinline__ void fma4(float4& acc, float a, float4 w) {
    acc.x = fmaf(a, w.x, acc.x); acc.y = fmaf(a, w.y, acc.y);
    acc.z = fmaf(a, w.z, acc.z); acc.w = fmaf(a, w.w, acc.w);
}

// ---------------- CSR build ----------------
__global__ void k_deg(const int* __restrict__ dst, int* __restrict__ deg) {
    int i = blockIdx.x * blockDim.x + threadIdx.x;
    if (i < EE) atomicAdd(&deg[dst[i]], 1);
}

__global__ void k_scan(const int* __restrict__ deg, int* __restrict__ rowptr,
                       int* __restrict__ cursor) {
    __shared__ int ts[1024];
    int t = threadIdx.x;
    const int CH = 30;                 // 1024*30 = 30720 >= 30000
    int base = t * CH;
    int s = 0;
    for (int i = 0; i < CH; ++i) {
        int idx = base + i;
        if (idx < NN) s += deg[idx];
    }
    ts[t] = s;
    __syncthreads();
    for (int off = 1; off < 1024; off <<= 1) {
        int v = (t >= off) ? ts[t - off] : 0;
        __syncthreads();
        ts[t] += v;
        __syncthreads();
    }
    int run = (t == 0) ? 0 : ts[t - 1];
    for (int i = 0; i < CH; ++i) {
        int idx = base + i;
        if (idx < NN) {
            rowptr[idx] = run;
            cursor[idx] = run;
            run += deg[idx];
        }
    }
    if (t == 1023) rowptr[NN] = ts[1023];
}

// scatter CSR-ordered per-edge records {src, eid, wl}; wl = eig-filter MLP
__global__ void k_scatter(const int* __restrict__ src, const int* __restrict__ dst,
                          const float* __restrict__ eig,
                          const float* __restrict__ W1, const float* __restrict__ b1,
                          const float* __restrict__ W2, const float* __restrict__ b2,
                          const float* __restrict__ W3, const float* __restrict__ b3,
                          int* __restrict__ cursor, int* __restrict__ csr_src,
                          int* __restrict__ csr_eid, float* __restrict__ csr_wl) {
    int i = blockIdx.x * blockDim.x + threadIdx.x;
    if (i >= EE) return;
    int dd = dst[i];
    int ss = src[i];
    int pos = atomicAdd(&cursor[dd], 1);
    csr_src[pos] = ss;
    csr_eid[pos] = i;

    float x[6];
    x[0] = eig[ss * 4 + 1]; x[1] = eig[ss * 4 + 2]; x[2] = eig[ss * 4 + 3];
    x[3] = eig[dd * 4 + 1]; x[4] = eig[dd * 4 + 2]; x[5] = eig[dd * 4 + 3];
    float a[3], bt[3];
    #pragma unroll
    for (int c = 0; c < 3; ++c) {
        float acc = b1[c];
        #pragma unroll
        for (int r = 0; r < 6; ++r) acc += x[r] * W1[r * 3 + c];
        a[c] = fmaxf(acc, 0.f);
    }
    #pragma unroll
    for (int c = 0; c < 3; ++c) {
        float acc = b2[c];
        #pragma unroll
        for (int r = 0; r < 3; ++r) acc += a[r] * W2[r * 3 + c];
        bt[c] = fmaxf(acc, 0.f);
    }
    float y = b3[0];
    #pragma unroll
    for (int r = 0; r < 3; ++r) y += bt[r] * W3[r];
    csr_wl[pos] = 1.f / (1.f + expf(-y));
}

// ---------------- k_pre: U = h @ W_pre[0:128], V = h @ W_pre[128:256] ----------------
__global__ __launch_bounds__(256) void k_pre(const float* __restrict__ h,
                                             const float* __restrict__ Wp,
                                             float* __restrict__ U,
                                             float* __restrict__ V) {
    __shared__ float At[16][132];
    int tid = threadIdx.x;
    int v0 = blockIdx.x * 16;          // grid exact: 1875*16 == 30000
    const float4* h4 = (const float4*)h;
    for (int i = tid; i < 16 * 32; i += 256) {
        int r = i >> 5, kq = i & 31;
        ((float4*)&At[r][0])[kq] = h4[(size_t)(v0 + r) * 32 + kq];
    }
    __syncthreads();

    int wave = tid >> 6, lane = tid & 63;
    int jloc = lane & 7, rrow = lane >> 3;
    int j4 = wave * 32 + jloc * 4;
    float4 aU[2], aV[2];
    aU[0] = make_float4(0,0,0,0); aU[1] = make_float4(0,0,0,0);
    aV[0] = make_float4(0,0,0,0); aV[1] = make_float4(0,0,0,0);

    #pragma unroll 4
    for (int k = 0; k < 128; ++k) {
        float4 wu = *(const float4*)(Wp + (size_t)k * 128 + j4);
        float4 wv = *(const float4*)(Wp + (size_t)(k + 128) * 128 + j4);
        float a0 = At[rrow][k], a1 = At[rrow + 8][k];
        fma4(aU[0], a0, wu); fma4(aU[1], a1, wu);
        fma4(aV[0], a0, wv); fma4(aV[1], a1, wv);
    }
    #pragma unroll
    for (int r = 0; r < 2; ++r) {
        int v = v0 + rrow + r * 8;
        *(float4*)(U + (size_t)v * 128 + j4) = aU[r];
        *(float4*)(V + (size_t)v * 128 + j4) = aV[r];
    }
}

// ---------------- k_fused: edge aggregation (into LDS) + post GEMM ----------------
// 512 threads (8 waves), 16 nodes/block, LDS 49.5 KB -> 3 blocks/CU = 24 waves/CU.
// Phase 1: wave w -> rows {2w, 2w+1}; lane owns channels {2*lane, 2*lane+1}.
// Phase 2: wave w -> cols [16w,16w+16); thread -> 1 row (rrow=lane>>2), 4 cols.
__device__ __forceinline__ void proj_ef2(const float4* __restrict__ q,
                                         const float2 wef[16],
                                         float& p0, float& p1) {
    float4 qa = q[0], qb = q[1], qc = q[2], qd = q[3];
    p0 = qa.x*wef[0].x + qa.y*wef[1].x + qa.z*wef[2].x + qa.w*wef[3].x
       + qb.x*wef[4].x + qb.y*wef[5].x + qb.z*wef[6].x + qb.w*wef[7].x
       + qc.x*wef[8].x + qc.y*wef[9].x + qc.z*wef[10].x + qc.w*wef[11].x
       + qd.x*wef[12].x + qd.y*wef[13].x + qd.z*wef[14].x + qd.w*wef[15].x;
    p1 = qa.x*wef[0].y + qa.y*wef[1].y + qa.z*wef[2].y + qa.w*wef[3].y
       + qb.x*wef[4].y + qb.y*wef[5].y + qb.z*wef[6].y + qb.w*wef[7].y
       + qc.x*wef[8].y + qc.y*wef[9].y + qc.z*wef[10].y + qc.w*wef[11].y
       + qd.x*wef[12].y + qd.y*wef[13].y + qd.z*wef[14].y + qd.w*wef[15].y;
}

__global__ __launch_bounds__(512, 6) void k_fused(
    const float* __restrict__ h, const float* __restrict__ U,
    const float* __restrict__ V, const float* __restrict__ ef,
    const float* __restrict__ b_pre, const float* __restrict__ W_pre,
    const int* __restrict__ csr_src, const int* __restrict__ rowptr,
    const int* __restrict__ csr_eid, const float* __restrict__ csr_wl,
    const float* __restrict__ Wp, const float* __restrict__ bpost,
    const float* __restrict__ snorm, float* __restrict__ out,
    float* __restrict__ colsum, float* __restrict__ colsq) {
    __shared__ float At[16][ATP];      // [r][0:128)=h, [r][128:768)=agg
    __shared__ float f1s[16], f2s[16];
    int tid = threadIdx.x;
    int v0 = blockIdx.x * 16;          // grid exact: 1875*16 == 30000

    // h tile: 512 threads, one float4 each
    {
        int r = tid >> 5, kq = tid & 31;
        ((float4*)&At[r][0])[kq] = ((const float4*)h)[(size_t)(v0 + r) * 32 + kq];
    }

    const int wave = tid >> 6;
    const int lane = tid & 63;

    // ---- phase 1 ----
    const float2* Wp2 = (const float2*)W_pre;      // [272][64] float2
    const float2* U2  = (const float2*)U;          // [NN][64] float2
    const float2* V2  = (const float2*)V;
    float2 wef[16];
    #pragma unroll
    for (int k = 0; k < 16; ++k) wef[k] = Wp2[(size_t)(256 + k) * 64 + lane];
    const float2 bb = ((const float2*)b_pre)[lane];
    const float4* ef4 = (const float4*)ef;

    for (int i = 0; i < 2; ++i) {
        int r = wave * 2 + i;
        int v = v0 + r;
        int rs = __builtin_amdgcn_readfirstlane(rowptr[v]);
        int re = __builtin_amdgcn_readfirstlane(rowptr[v + 1]);
        int d  = re - rs;

        float2 pv = V2[(size_t)v * 64 + lane];
        float pd0 = pv.x + bb.x, pd1 = pv.y + bb.y;

        float sum0 = 0.f, sum1 = 0.f, sq0 = 0.f, sq1 = 0.f, el0 = 0.f, el1 = 0.f;
        float mx0 = -INFINITY, mx1 = -INFINITY, mn0 = INFINITY, mn1 = INFINITY;

        int t = 0;
        for (; t + 4 <= d; t += 4) {
            int s0 = csr_src[rs+t+0], s1 = csr_src[rs+t+1];
            int s2 = csr_src[rs+t+2], s3 = csr_src[rs+t+3];
            int e0 = csr_eid[rs+t+0], e1 = csr_eid[rs+t+1];
            int e2 = csr_eid[rs+t+2], e3 = csr_eid[rs+t+3];
            float wl0 = csr_wl[rs+t+0], wl1 = csr_wl[rs+t+1];
            float wl2 = csr_wl[rs+t+2], wl3 = csr_wl[rs+t+3];
            float2 u0 = U2[(size_t)s0 * 64 + lane];
            float2 u1 = U2[(size_t)s1 * 64 + lane];
            float2 u2 = U2[(size_t)s2 * 64 + lane];
            float2 u3 = U2[(size_t)s3 * 64 + lane];

            float p0, p1;
            proj_ef2(ef4 + (size_t)e0 * 4, wef, p0, p1);
            {
                float a0 = pd0 + u0.x + p0, a1 = pd1 + u0.y + p1;
                sum0 += a0; sum1 += a1;
                sq0 = fmaf(a0, a0, sq0); sq1 = fmaf(a1, a1, sq1);
                mx0 = fmaxf(mx0, a0); mx1 = fmaxf(mx1, a1);
                mn0 = fminf(mn0, a0); mn1 = fminf(mn1, a1);
                el0 = fmaf(a0, wl0, el0); el1 = fmaf(a1, wl0, el1);
            }
            proj_ef2(ef4 + (size_t)e1 * 4, wef, p0, p1);
            {
                float a0 = pd0 + u1.x + p0, a1 = pd1 + u1.y + p1;
                sum0 += a0; sum1 += a1;
                sq0 = fmaf(a0, a0, sq0); sq1 = fmaf(a1, a1, sq1);
                mx0 = fmaxf(mx0, a0); mx1 = fmaxf(mx1, a1);
                mn0 = fminf(mn0, a0); mn1 = fminf(mn1, a1);
                el0 = fmaf(a0, wl1, el0); el1 = fmaf(a1, wl1, el1);
            }
            proj_ef2(ef4 + (size_t)e2 * 4, wef, p0, p1);
            {
                float a0 = pd0 + u2.x + p0, a1 = pd1 + u2.y + p1;
                sum0 += a0; sum1 += a1;
                sq0 = fmaf(a0, a0, sq0); sq1 = fmaf(a1, a1, sq1);
                mx0 = fmaxf(mx0, a0); mx1 = fmaxf(mx1, a1);
                mn0 = fminf(mn0, a0); mn1 = fminf(mn1, a1);
                el0 = fmaf(a0, wl2, el0); el1 = fmaf(a1, wl2, el1);
            }
            proj_ef2(ef4 + (size_t)e3 * 4, wef, p0, p1);
            {
                float a0 = pd0 + u3.x + p0, a1 = pd1 + u3.y + p1;
                sum0 += a0; sum1 += a1;
                sq0 = fmaf(a0, a0, sq0); sq1 = fmaf(a1, a1, sq1);
                mx0 = fmaxf(mx0, a0); mx1 = fmaxf(mx1, a1);
                mn0 = fminf(mn0, a0); mn1 = fminf(mn1, a1);
                el0 = fmaf(a0, wl3, el0); el1 = fmaf(a1, wl3, el1);
            }
        }
        for (; t < d; ++t) {
            int s0 = csr_src[rs + t];
            int e0 = csr_eid[rs + t];
            float wl0 = csr_wl[rs + t];
            float2 u0 = U2[(size_t)s0 * 64 + lane];
            float p0, p1;
            proj_ef2(ef4 + (size_t)e0 * 4, wef, p0, p1);
            float a0 = pd0 + u0.x + p0, a1 = pd1 + u0.y + p1;
            sum0 += a0; sum1 += a1;
            sq0 = fmaf(a0, a0, sq0); sq1 = fmaf(a1, a1, sq1);
            mx0 = fmaxf(mx0, a0); mx1 = fmaxf(mx1, a1);
            mn0 = fminf(mn0, a0); mn1 = fminf(mn1, a1);
            el0 = fmaf(a0, wl0, el0); el1 = fmaf(a1, wl0, el1);
        }

        float2* Ar2 = (float2*)&At[r][128];   // agg = [mean|max|min|std|el] x 128
        if (d > 0) {
            float inv = 1.f / (float)d;
            float m0 = sum0 * inv, m1 = sum1 * inv;
            float vv0 = fmaxf(sq0 * inv - m0 * m0, 0.f);
            float vv1 = fmaxf(sq1 * inv - m1 * m1, 0.f);
            Ar2[lane]       = make_float2(m0, m1);
            Ar2[64 + lane]  = make_float2(mx0, mx1);
            Ar2[128 + lane] = make_float2(mn0, mn1);
            Ar2[192 + lane] = make_float2(sqrtf(vv0 + EPSF), sqrtf(vv1 + EPSF));
            Ar2[256 + lane] = make_float2(el0, el1);
            if (lane == 0) {
                float ld = logf((float)d + 1.f);
                f1s[r] = ld / AVG_D_LOG;
                f2s[r] = AVG_D_LOG / ld;
            }
        } else {
            #pragma unroll
            for (int s5 = 0; s5 < 5; ++s5) Ar2[s5 * 64 + lane] = make_float2(0.f, 0.f);
            if (lane == 0) { f1s[r] = 0.f; f2s[r] = 0.f; }
        }
    }
    __syncthreads();

    // ---- phase 2: GEMM. wave -> 16 cols, thread -> 1 row x 4 cols ----
    int jloc = lane & 3, rrow = lane >> 2;
    int j4 = wave * 16 + jloc * 4;
    float4 acc0 = make_float4(0,0,0,0);
    float4 acc1 = make_float4(0,0,0,0);
    float4 acc2 = make_float4(0,0,0,0);

    #pragma unroll 4
    for (int k = 0; k < 128; ++k) {
        float4 w0 = *(const float4*)(Wp + (size_t)k * 128 + j4);
        float a = At[rrow][k];
        fma4(acc0, a, w0);
    }
    #pragma unroll 2
    for (int k = 128; k < 768; ++k) {
        float4 w0 = *(const float4*)(Wp + (size_t)k * 128 + j4);
        float4 w1 = *(const float4*)(Wp + (size_t)(k + 640) * 128 + j4);
        float4 w2 = *(const float4*)(Wp + (size_t)(k + 1280) * 128 + j4);
        float a = At[rrow][k];
        fma4(acc0, a, w0);
        fma4(acc1, a, w1);
        fma4(acc2, a, w2);
    }

    float4 bj = *(const float4*)(bpost + j4);
    int v = v0 + rrow;
    float f1 = f1s[rrow], f2 = f2s[rrow], sn = snorm[v];
    float4 o;
    o.x = (acc0.x + bj.x + f1 * acc1.x + f2 * acc2.x) * sn;
    o.y = (acc0.y + bj.y + f1 * acc1.y + f2 * acc2.y) * sn;
    o.z = (acc0.z + bj.z + f1 * acc1.z + f2 * acc2.z) * sn;
    o.w = (acc0.w + bj.w + f1 * acc1.w + f2 * acc2.w) * sn;
    *(float4*)(out + (size_t)v * 128 + j4) = o;

    __syncthreads();                    // all At reads complete
    float* redS = &At[0][0];            // alias dead A-tile: [16][128]
    float* redQ = redS + 2048;          // [16][128]
    redS[rrow * 128 + j4 + 0] = o.x; redQ[rrow * 128 + j4 + 0] = o.x * o.x;
    redS[rrow * 128 + j4 + 1] = o.y; redQ[rrow * 128 + j4 + 1] = o.y * o.y;
    redS[rrow * 128 + j4 + 2] = o.z; redQ[rrow * 128 + j4 + 2] = o.z * o.z;
    redS[rrow * 128 + j4 + 3] = o.w; redQ[rrow * 128 + j4 + 3] = o.w * o.w;
    __syncthreads();
    if (tid < 128) {
        float s = 0.f, q = 0.f;
        #pragma unroll
        for (int g = 0; g < 16; ++g) { s += redS[g * 128 + tid]; q += redQ[g * 128 + tid]; }
        atomicAdd(&colsum[tid], s);
        atomicAdd(&colsq[tid], q);
    }
}

// ---------------- column batch-norm (float4) ----------------
__global__ void k_norm(float* __restrict__ out, const float* __restrict__ colsum,
                       const float* __restrict__ colsq, const float* __restrict__ gamma,
                       const float* __restrict__ beta) {
    int i = blockIdx.x * 256 + threadIdx.x;     // 960000 float4s
    if (i >= NN * 32) return;
    int jq = i & 31;
    float4 cs = ((const float4*)colsum)[jq];
    float4 cq = ((const float4*)colsq)[jq];
    float4 gm = ((const float4*)gamma)[jq];
    float4 bt = ((const float4*)beta)[jq];
    float4 o = ((float4*)out)[i];
    const float invN = 1.f / NN;
    float mu, var, inv;
    mu = cs.x * invN; var = fmaxf(cq.x * invN - mu * mu, 0.f); inv = 1.f / sqrtf(var + 1e-5f);
    o.x = (o.x - mu) * inv * gm.x + bt.x;
    mu = cs.y * invN; var = fmaxf(cq.y * invN - mu * mu, 0.f); inv = 1.f / sqrtf(var + 1e-5f);
    o.y = (o.y - mu) * inv * gm.y + bt.y;
    mu = cs.z * invN; var = fmaxf(cq.z * invN - mu * mu, 0.f); inv = 1.f / sqrtf(var + 1e-5f);
    o.z = (o.z - mu) * inv * gm.z + bt.z;
    mu = cs.w * invN; var = fmaxf(cq.w * invN - mu * mu, 0.f); inv = 1.f / sqrtf(var + 1e-5f);
    o.w = (o.w - mu) * inv * gm.w + bt.w;
    ((float4*)out)[i] = o;
}

static inline size_t align256(size_t x) { return (x + 255) & ~(size_t)255; }

extern "C" void kernel_launch(void* const* d_in, const int* in_sizes, int n_in,
                              void* d_out, int out_size, void* d_ws, size_t ws_size,
                              hipStream_t stream) {
    const float* h      = (const float*)d_in[0];
    const float* eig    = (const float*)d_in[1];
    const float* ef     = (const float*)d_in[2];
    const int*   src    = (const int*)d_in[3];
    const int*   dst    = (const int*)d_in[4];
    const float* snorm  = (const float*)d_in[5];
    const float* W_pre  = (const float*)d_in[6];
    const float* b_pre  = (const float*)d_in[7];
    const float* ftW1   = (const float*)d_in[8];
    const float* ftb1   = (const float*)d_in[9];
    const float* ftW2   = (const float*)d_in[10];
    const float* ftb2   = (const float*)d_in[11];
    const float* ftW3   = (const float*)d_in[12];
    const float* ftb3   = (const float*)d_in[13];
    const float* W_post = (const float*)d_in[14];
    const float* b_post = (const float*)d_in[15];
    const float* gamma  = (const float*)d_in[16];
    const float* beta   = (const float*)d_in[17];
    float* out = (float*)d_out;

    char* ws = (char*)d_ws;
    size_t off = 0;
    int* rowptr   = (int*)(ws + off); off += align256((NN + 1) * 4);
    int* cursor   = (int*)(ws + off); off += align256(NN * 4);
    int* deg      = (int*)(ws + off); off += align256(NN * 4);
    int* csr_src  = (int*)(ws + off); off += align256((size_t)EE * 4);
    int* csr_eid  = (int*)(ws + off); off += align256((size_t)EE * 4);
    float* csr_wl = (float*)(ws + off); off += align256((size_t)EE * 4);
    float* colsum = (float*)(ws + off); off += 512;
    float* colsq  = (float*)(ws + off); off += 512;
    float* U      = (float*)(ws + off); off += (size_t)NN * 128 * 4;
    float* V      = (float*)(ws + off); off += (size_t)NN * 128 * 4;
    // total ~= 37 MB

    hipMemsetAsync(deg, 0, NN * 4, stream);
    hipMemsetAsync(colsum, 0, 1024, stream);   // colsum + colsq contiguous

    k_deg<<<1875, 256, 0, stream>>>(dst, deg);
    k_scan<<<1, 1024, 0, stream>>>(deg, rowptr, cursor);
    k_scatter<<<1875, 256, 0, stream>>>(src, dst, eig, ftW1, ftb1, ftW2, ftb2,
                                        ftW3, ftb3, cursor, csr_src, csr_eid, csr_wl);
    k_pre<<<1875, 256, 0, stream>>>(h, W_pre, U, V);
    k_fused<<<1875, 512, 0, stream>>>(h, U, V, ef, b_pre, W_pre, csr_src, rowptr,
                                      csr_eid, csr_wl, W_post, b_post, snorm, out,
                                      colsum, colsq);
    k_norm<<<3750, 256, 0, stream>>>(out, colsum, colsq, gamma, beta);
}

// Round 7
// 581.045 us; speedup vs baseline: 2.1121x; 2.1121x over previous
//
#include <hip/hip_runtime.h>
#include <math.h>

#define NN 30000
#define EE 480000
#define AVG_D_LOG 2.833f
#define EPSF 1e-5f

__device__ __forceinline__ void fma4(float4& acc, float a, float4 w) {
    acc.x = fmaf(a, w.x, acc.x); acc.y = fmaf(a, w.y, acc.y);
    acc.z = fmaf(a, w.z, acc.z); acc.w = fmaf(a, w.w, acc.w);
}

// ---------------- CSR build ----------------
__global__ void k_deg(const int* __restrict__ dst, int* __restrict__ deg) {
    int i = blockIdx.x * blockDim.x + threadIdx.x;
    if (i < EE) atomicAdd(&deg[dst[i]], 1);
}

__global__ void k_scan(const int* __restrict__ deg, int* __restrict__ rowptr,
                       int* __restrict__ cursor) {
    __shared__ int ts[1024];
    int t = threadIdx.x;
    const int CH = 30;                 // 1024*30 = 30720 >= 30000
    int base = t * CH;
    int s = 0;
    for (int i = 0; i < CH; ++i) {
        int idx = base + i;
        if (idx < NN) s += deg[idx];
    }
    ts[t] = s;
    __syncthreads();
    for (int off = 1; off < 1024; off <<= 1) {
        int v = (t >= off) ? ts[t - off] : 0;
        __syncthreads();
        ts[t] += v;
        __syncthreads();
    }
    int run = (t == 0) ? 0 : ts[t - 1];
    for (int i = 0; i < CH; ++i) {
        int idx = base + i;
        if (idx < NN) {
            rowptr[idx] = run;
            cursor[idx] = run;
            run += deg[idx];
        }
    }
    if (t == 1023) rowptr[NN] = ts[1023];
}

// scatter CSR-ordered per-edge records {src, eid, wl}; wl = eig-filter MLP
__global__ void k_scatter(const int* __restrict__ src, const int* __restrict__ dst,
                          const float* __restrict__ eig,
                          const float* __restrict__ W1, const float* __restrict__ b1,
                          const float* __restrict__ W2, const float* __restrict__ b2,
                          const float* __restrict__ W3, const float* __restrict__ b3,
                          int* __restrict__ cursor, int* __restrict__ csr_src,
                          int* __restrict__ csr_eid, float* __restrict__ csr_wl) {
    int i = blockIdx.x * blockDim.x + threadIdx.x;
    if (i >= EE) return;
    int dd = dst[i];
    int ss = src[i];
    int pos = atomicAdd(&cursor[dd], 1);
    csr_src[pos] = ss;
    csr_eid[pos] = i;

    float x[6];
    x[0] = eig[ss * 4 + 1]; x[1] = eig[ss * 4 + 2]; x[2] = eig[ss * 4 + 3];
    x[3] = eig[dd * 4 + 1]; x[4] = eig[dd * 4 + 2]; x[5] = eig[dd * 4 + 3];
    float a[3], bt[3];
    #pragma unroll
    for (int c = 0; c < 3; ++c) {
        float acc = b1[c];
        #pragma unroll
        for (int r = 0; r < 6; ++r) acc += x[r] * W1[r * 3 + c];
        a[c] = fmaxf(acc, 0.f);
    }
    #pragma unroll
    for (int c = 0; c < 3; ++c) {
        float acc = b2[c];
        #pragma unroll
        for (int r = 0; r < 3; ++r) acc += a[r] * W2[r * 3 + c];
        bt[c] = fmaxf(acc, 0.f);
    }
    float y = b3[0];
    #pragma unroll
    for (int r = 0; r < 3; ++r) y += bt[r] * W3[r];
    csr_wl[pos] = 1.f / (1.f + expf(-y));
}

// ---------------- k_pre: [U|V] = h[30000x128] @ W'[128x256] ----------------
// W'[k][j] = W_pre[k][j] (j<128) | W_pre[128+k][j-128].  64 rows/block, 512 thr.
// Cooperative LDS staging, all global loads lane-distinct float4 (1KB/wave-load).
#define PBK 32
__global__ __launch_bounds__(512) void k_pre(const float* __restrict__ h,
                                             const float* __restrict__ Wp,
                                             float* __restrict__ U,
                                             float* __restrict__ V) {
    __shared__ float Ws[PBK][256];     // 32 KB
    __shared__ float As[PBK][68];      // 8.7 KB (pad 68)
    int tid = threadIdx.x;
    int v0 = blockIdx.x * 64;

    const float4* h4  = (const float4*)h;
    const float4* Wp4 = (const float4*)Wp;
    const int ar  = tid >> 3;          // 0..63 A row
    const int akq = tid & 7;           // 0..7  A k-quad
    const int wk  = tid >> 4;          // 0..31 W k-row
    const int wq  = tid & 15;          // 0..15 W col-quad group
    const int jg  = tid & 63;          // 0..63 out col-quad
    const int rg  = tid >> 6;          // 0..7  out row-group (8 rows)

    float4 acc[8];
    #pragma unroll
    for (int i = 0; i < 8; ++i) acc[i] = make_float4(0, 0, 0, 0);

    float4 aR = make_float4(0, 0, 0, 0);
    float4 wW[4];

    auto LOAD = [&](int s) {
        int k0 = s * PBK;
        int vA = v0 + ar;
        aR = (vA < NN) ? h4[(size_t)vA * 32 + (k0 >> 2) + akq] : make_float4(0, 0, 0, 0);
        #pragma unroll
        for (int m = 0; m < 4; ++m) {
            int q = wq + 16 * m;       // 0..63 col-quad of W'
            wW[m] = (q < 32) ? Wp4[(size_t)(k0 + wk) * 32 + q]
                             : Wp4[(size_t)(128 + k0 + wk) * 32 + (q - 32)];
        }
    };
    auto WRITE = [&]() {
        As[akq * 4 + 0][ar] = aR.x;
        As[akq * 4 + 1][ar] = aR.y;
        As[akq * 4 + 2][ar] = aR.z;
        As[akq * 4 + 3][ar] = aR.w;
        #pragma unroll
        for (int m = 0; m < 4; ++m)
            *(float4*)&Ws[wk][(wq + 16 * m) * 4] = wW[m];
    };

    LOAD(0);
    for (int s = 0; s < 4; ++s) {
        WRITE();
        __syncthreads();
        if (s + 1 < 4) LOAD(s + 1);
        #pragma unroll
        for (int kk = 0; kk < PBK; ++kk) {
            float4 w  = *(const float4*)&Ws[kk][jg * 4];
            float4 a0 = *(const float4*)&As[kk][rg * 8];       // broadcast
            float4 a1 = *(const float4*)&As[kk][rg * 8 + 4];
            fma4(acc[0], a0.x, w); fma4(acc[1], a0.y, w);
            fma4(acc[2], a0.z, w); fma4(acc[3], a0.w, w);
            fma4(acc[4], a1.x, w); fma4(acc[5], a1.y, w);
            fma4(acc[6], a1.z, w); fma4(acc[7], a1.w, w);
        }
        __syncthreads();
    }

    #pragma unroll
    for (int i = 0; i < 8; ++i) {
        int v = v0 + rg * 8 + i;
        if (v < NN) {
            if (jg < 32) *(float4*)(U + (size_t)v * 128 + jg * 4)         = acc[i];
            else         *(float4*)(V + (size_t)v * 128 + (jg - 32) * 4)  = acc[i];
        }
    }
}

// ---------------- k_agg: one wave per node, agg row + f1/f2 ----------------
__device__ __forceinline__ void proj_ef2(const float4* __restrict__ q,
                                         const float2 wef[16],
                                         float& p0, float& p1) {
    float4 qa = q[0], qb = q[1], qc = q[2], qd = q[3];
    p0 = qa.x*wef[0].x + qa.y*wef[1].x + qa.z*wef[2].x + qa.w*wef[3].x
       + qb.x*wef[4].x + qb.y*wef[5].x + qb.z*wef[6].x + qb.w*wef[7].x
       + qc.x*wef[8].x + qc.y*wef[9].x + qc.z*wef[10].x + qc.w*wef[11].x
       + qd.x*wef[12].x + qd.y*wef[13].x + qd.z*wef[14].x + qd.w*wef[15].x;
    p1 = qa.x*wef[0].y + qa.y*wef[1].y + qa.z*wef[2].y + qa.w*wef[3].y
       + qb.x*wef[4].y + qb.y*wef[5].y + qb.z*wef[6].y + qb.w*wef[7].y
       + qc.x*wef[8].y + qc.y*wef[9].y + qc.z*wef[10].y + qc.w*wef[11].y
       + qd.x*wef[12].y + qd.y*wef[13].y + qd.z*wef[14].y + qd.w*wef[15].y;
}

__global__ __launch_bounds__(256) void k_agg(
    const float* __restrict__ U, const float* __restrict__ V,
    const float* __restrict__ ef, const float* __restrict__ b_pre,
    const float* __restrict__ W_pre, const int* __restrict__ csr_src,
    const int* __restrict__ rowptr, const int* __restrict__ csr_eid,
    const float* __restrict__ csr_wl,
    float* __restrict__ agg, float* __restrict__ f1v, float* __restrict__ f2v,
    int vb, int vcap) {
    int tid = threadIdx.x;
    const int wave = tid >> 6;
    const int lane = tid & 63;
    int v = vb + blockIdx.x * 4 + wave;
    if (v >= vcap) return;

    const float2* Wp2 = (const float2*)W_pre;      // [272][64] float2
    const float2* U2  = (const float2*)U;          // [NN][64] float2
    const float2* V2  = (const float2*)V;
    float2 wef[16];
    #pragma unroll
    for (int k = 0; k < 16; ++k) wef[k] = Wp2[(size_t)(256 + k) * 64 + lane];
    const float2 bb = ((const float2*)b_pre)[lane];
    const float4* ef4 = (const float4*)ef;

    int rs = __builtin_amdgcn_readfirstlane(rowptr[v]);
    int re = __builtin_amdgcn_readfirstlane(rowptr[v + 1]);
    int d  = re - rs;

    float2 pv = V2[(size_t)v * 64 + lane];
    float pd0 = pv.x + bb.x, pd1 = pv.y + bb.y;

    float sum0 = 0.f, sum1 = 0.f, sq0 = 0.f, sq1 = 0.f, el0 = 0.f, el1 = 0.f;
    float mx0 = -INFINITY, mx1 = -INFINITY, mn0 = INFINITY, mn1 = INFINITY;

    int t = 0;
    for (; t + 4 <= d; t += 4) {
        int s0 = csr_src[rs+t+0], s1 = csr_src[rs+t+1];
        int s2 = csr_src[rs+t+2], s3 = csr_src[rs+t+3];
        int e0 = csr_eid[rs+t+0], e1 = csr_eid[rs+t+1];
        int e2 = csr_eid[rs+t+2], e3 = csr_eid[rs+t+3];
        float wl0 = csr_wl[rs+t+0], wl1 = csr_wl[rs+t+1];
        float wl2 = csr_wl[rs+t+2], wl3 = csr_wl[rs+t+3];
        float2 u0 = U2[(size_t)s0 * 64 + lane];
        float2 u1 = U2[(size_t)s1 * 64 + lane];
        float2 u2 = U2[(size_t)s2 * 64 + lane];
        float2 u3 = U2[(size_t)s3 * 64 + lane];

        float p0, p1;
        proj_ef2(ef4 + (size_t)e0 * 4, wef, p0, p1);
        {
            float a0 = pd0 + u0.x + p0, a1 = pd1 + u0.y + p1;
            sum0 += a0; sum1 += a1;
            sq0 = fmaf(a0, a0, sq0); sq1 = fmaf(a1, a1, sq1);
            mx0 = fmaxf(mx0, a0); mx1 = fmaxf(mx1, a1);
            mn0 = fminf(mn0, a0); mn1 = fminf(mn1, a1);
            el0 = fmaf(a0, wl0, el0); el1 = fmaf(a1, wl0, el1);
        }
        proj_ef2(ef4 + (size_t)e1 * 4, wef, p0, p1);
        {
            float a0 = pd0 + u1.x + p0, a1 = pd1 + u1.y + p1;
            sum0 += a0; sum1 += a1;
            sq0 = fmaf(a0, a0, sq0); sq1 = fmaf(a1, a1, sq1);
            mx0 = fmaxf(mx0, a0); mx1 = fmaxf(mx1, a1);
            mn0 = fminf(mn0, a0); mn1 = fminf(mn1, a1);
            el0 = fmaf(a0, wl1, el0); el1 = fmaf(a1, wl1, el1);
        }
        proj_ef2(ef4 + (size_t)e2 * 4, wef, p0, p1);
        {
            float a0 = pd0 + u2.x + p0, a1 = pd1 + u2.y + p1;
            sum0 += a0; sum1 += a1;
            sq0 = fmaf(a0, a0, sq0); sq1 = fmaf(a1, a1, sq1);
            mx0 = fmaxf(mx0, a0); mx1 = fmaxf(mx1, a1);
            mn0 = fminf(mn0, a0); mn1 = fminf(mn1, a1);
            el0 = fmaf(a0, wl2, el0); el1 = fmaf(a1, wl2, el1);
        }
        proj_ef2(ef4 + (size_t)e3 * 4, wef, p0, p1);
        {
            float a0 = pd0 + u3.x + p0, a1 = pd1 + u3.y + p1;
            sum0 += a0; sum1 += a1;
            sq0 = fmaf(a0, a0, sq0); sq1 = fmaf(a1, a1, sq1);
            mx0 = fmaxf(mx0, a0); mx1 = fmaxf(mx1, a1);
            mn0 = fminf(mn0, a0); mn1 = fminf(mn1, a1);
            el0 = fmaf(a0, wl3, el0); el1 = fmaf(a1, wl3, el1);
        }
    }
    for (; t < d; ++t) {
        int s0 = csr_src[rs + t];
        int e0 = csr_eid[rs + t];
        float wl0 = csr_wl[rs + t];
        float2 u0 = U2[(size_t)s0 * 64 + lane];
        float p0, p1;
        proj_ef2(ef4 + (size_t)e0 * 4, wef, p0, p1);
        float a0 = pd0 + u0.x + p0, a1 = pd1 + u0.y + p1;
        sum0 += a0; sum1 += a1;
        sq0 = fmaf(a0, a0, sq0); sq1 = fmaf(a1, a1, sq1);
        mx0 = fmaxf(mx0, a0); mx1 = fmaxf(mx1, a1);
        mn0 = fminf(mn0, a0); mn1 = fminf(mn1, a1);
        el0 = fmaf(a0, wl0, el0); el1 = fmaf(a1, wl0, el1);
    }

    float2* Ar2 = (float2*)(agg + (size_t)(v - vb) * 640);
    if (d > 0) {
        float inv = 1.f / (float)d;
        float m0 = sum0 * inv, m1 = sum1 * inv;
        float vv0 = fmaxf(sq0 * inv - m0 * m0, 0.f);
        float vv1 = fmaxf(sq1 * inv - m1 * m1, 0.f);
        Ar2[lane]       = make_float2(m0, m1);
        Ar2[64 + lane]  = make_float2(mx0, mx1);
        Ar2[128 + lane] = make_float2(mn0, mn1);
        Ar2[192 + lane] = make_float2(sqrtf(vv0 + EPSF), sqrtf(vv1 + EPSF));
        Ar2[256 + lane] = make_float2(el0, el1);
        if (lane == 0) {
            float ld = logf((float)d + 1.f);
            f1v[v] = ld / AVG_D_LOG;
            f2v[v] = AVG_D_LOG / ld;
        }
    } else {
        #pragma unroll
        for (int s5 = 0; s5 < 5; ++s5) Ar2[s5 * 64 + lane] = make_float2(0.f, 0.f);
        if (lane == 0) { f1v[v] = 0.f; f2v[v] = 0.f; }
    }
}

// ---------------- k_gemm: out = A_eff[rows x 2048] @ W_post[2048x128] ----------------
// A_eff = [h | agg | f1*agg | f2*agg] (f folded at LDS-stage). 64 rows x 128 cols,
// 512 thr; thread: 4 rows x 4 cols. Double-buffered LDS; all global loads lane-distinct.
#define BM 64
#define BK 32
__global__ __launch_bounds__(512) void k_gemm(
    const float* __restrict__ h, const float* __restrict__ agg,
    const float* __restrict__ f1v, const float* __restrict__ f2v,
    const float* __restrict__ Wp, const float* __restrict__ bpost,
    const float* __restrict__ snorm, float* __restrict__ out,
    float* __restrict__ colsum, float* __restrict__ colsq,
    int vb, int vcap) {
    __shared__ float Ws[2][BK][128];   // 32 KB
    __shared__ float As[2][BK][68];    // 17.4 KB
    __shared__ float f1sh[BM], f2sh[BM];
    int tid = threadIdx.x;
    int v0 = vb + blockIdx.x * BM;

    if (tid < BM) {
        int v = v0 + tid;
        f1sh[tid] = (v < vcap) ? f1v[v] : 0.f;
        f2sh[tid] = (v < vcap) ? f2v[v] : 0.f;
    }

    const float4* h4 = (const float4*)h;
    const float4* agg4 = (const float4*)agg;
    const float4* Wp4 = (const float4*)Wp;
    const int ar  = tid >> 3;          // 0..63: A row
    const int akq = tid & 7;           // 0..7:  A k-quad
    const int wkk = tid >> 5;          // 0..15: W k-row (two: wkk, wkk+16)
    const int wjq = tid & 31;          // 0..31: W col-quad

    const int jg = tid & 31, rg = tid >> 5;
    const int j4 = jg * 4, r4 = rg * 4;
    float4 acc[4];
    acc[0] = make_float4(0,0,0,0); acc[1] = make_float4(0,0,0,0);
    acc[2] = make_float4(0,0,0,0); acc[3] = make_float4(0,0,0,0);

    float4 aR = make_float4(0,0,0,0), wR0, wR1;
    auto LOAD = [&](int s) {
        int k0 = s * BK;
        int vA = v0 + ar;
        float4 av = make_float4(0,0,0,0);
        if (vA < vcap) {
            size_t arow = (size_t)(vA - vb) * 160;
            if (k0 < 128) {
                av = h4[(size_t)vA * 32 + (k0 >> 2) + akq];
            } else if (k0 < 768) {
                av = agg4[arow + ((k0 - 128) >> 2) + akq];
            } else if (k0 < 1408) {
                av = agg4[arow + ((k0 - 768) >> 2) + akq];
                float f = f1sh[ar];
                av.x *= f; av.y *= f; av.z *= f; av.w *= f;
            } else {
                av = agg4[arow + ((k0 - 1408) >> 2) + akq];
                float f = f2sh[ar];
                av.x *= f; av.y *= f; av.z *= f; av.w *= f;
            }
        }
        aR = av;
        wR0 = Wp4[(size_t)(k0 + wkk) * 32 + wjq];
        wR1 = Wp4[(size_t)(k0 + 16 + wkk) * 32 + wjq];
    };
    auto WRITE = [&](int buf) {
        As[buf][akq * 4 + 0][ar] = aR.x;
        As[buf][akq * 4 + 1][ar] = aR.y;
        As[buf][akq * 4 + 2][ar] = aR.z;
        As[buf][akq * 4 + 3][ar] = aR.w;
        *(float4*)&Ws[buf][wkk][wjq * 4]      = wR0;
        *(float4*)&Ws[buf][wkk + 16][wjq * 4] = wR1;
    };

    __syncthreads();          // f1sh/f2sh visible
    LOAD(0); WRITE(0);
    __syncthreads();

    for (int s = 0; s < 64; ++s) {
        int cur = s & 1;
        if (s + 1 < 64) LOAD(s + 1);           // issue global loads early
        #pragma unroll 8
        for (int kk = 0; kk < BK; ++kk) {
            float4 w = *(const float4*)&Ws[cur][kk][j4];
            float4 a = *(const float4*)&As[cur][kk][r4];   // broadcast
            fma4(acc[0], a.x, w); fma4(acc[1], a.y, w);
            fma4(acc[2], a.z, w); fma4(acc[3], a.w, w);
        }
        if (s + 1 < 64) WRITE(cur ^ 1);        // vmcnt wait lands here
        __syncthreads();
    }

    // ---- epilogue: bias, snorm, out, column sums ----
    float* redS = &Ws[0][0][0];        // alias dead W buffers
    float* redQ = redS + 2048;
    float4 bj = ((const float4*)bpost)[jg];
    float ps[4] = {0.f,0.f,0.f,0.f}, pq[4] = {0.f,0.f,0.f,0.f};
    #pragma unroll
    for (int i = 0; i < 4; ++i) {
        int v = v0 + r4 + i;
        if (v < vcap) {
            float sn = snorm[v];
            float4 o;
            o.x = (acc[i].x + bj.x) * sn;
            o.y = (acc[i].y + bj.y) * sn;
            o.z = (acc[i].z + bj.z) * sn;
            o.w = (acc[i].w + bj.w) * sn;
            ((float4*)out)[(size_t)v * 32 + jg] = o;
            ps[0] += o.x; pq[0] += o.x * o.x;
            ps[1] += o.y; pq[1] += o.y * o.y;
            ps[2] += o.z; pq[2] += o.z * o.z;
            ps[3] += o.w; pq[3] += o.w * o.w;
        }
    }
    #pragma unroll
    for (int c = 0; c < 4; ++c) {
        redS[rg * 128 + j4 + c] = ps[c];
        redQ[rg * 128 + j4 + c] = pq[c];
    }
    __syncthreads();
    if (tid < 128) {
        float s = 0.f, q = 0.f;
        #pragma unroll
        for (int g = 0; g < 16; ++g) { s += redS[g * 128 + tid]; q += redQ[g * 128 + tid]; }
        atomicAdd(&colsum[tid], s);
        atomicAdd(&colsq[tid], q);
    }
}

// ---------------- column batch-norm (float4) ----------------
__global__ void k_norm(float* __restrict__ out, const float* __restrict__ colsum,
                       const float* __restrict__ colsq, const float* __restrict__ gamma,
                       const float* __restrict__ beta) {
    int i = blockIdx.x * 256 + threadIdx.x;     // 960000 float4s
    if (i >= NN * 32) return;
    int jq = i & 31;
    float4 cs = ((const float4*)colsum)[jq];
    float4 cq = ((const float4*)colsq)[jq];
    float4 gm = ((const float4*)gamma)[jq];
    float4 bt = ((const float4*)beta)[jq];
    float4 o = ((float4*)out)[i];
    const float invN = 1.f / NN;
    float mu, var, inv;
    mu = cs.x * invN; var = fmaxf(cq.x * invN - mu * mu, 0.f); inv = 1.f / sqrtf(var + 1e-5f);
    o.x = (o.x - mu) * inv * gm.x + bt.x;
    mu = cs.y * invN; var = fmaxf(cq.y * invN - mu * mu, 0.f); inv = 1.f / sqrtf(var + 1e-5f);
    o.y = (o.y - mu) * inv * gm.y + bt.y;
    mu = cs.z * invN; var = fmaxf(cq.z * invN - mu * mu, 0.f); inv = 1.f / sqrtf(var + 1e-5f);
    o.z = (o.z - mu) * inv * gm.z + bt.z;
    mu = cs.w * invN; var = fmaxf(cq.w * invN - mu * mu, 0.f); inv = 1.f / sqrtf(var + 1e-5f);
    o.w = (o.w - mu) * inv * gm.w + bt.w;
    ((float4*)out)[i] = o;
}

static inline size_t align256(size_t x) { return (x + 255) & ~(size_t)255; }

extern "C" void kernel_launch(void* const* d_in, const int* in_sizes, int n_in,
                              void* d_out, int out_size, void* d_ws, size_t ws_size,
                              hipStream_t stream) {
    const float* h      = (const float*)d_in[0];
    const float* eig    = (const float*)d_in[1];
    const float* ef     = (const float*)d_in[2];
    const int*   src    = (const int*)d_in[3];
    const int*   dst    = (const int*)d_in[4];
    const float* snorm  = (const float*)d_in[5];
    const float* W_pre  = (const float*)d_in[6];
    const float* b_pre  = (const float*)d_in[7];
    const float* ftW1   = (const float*)d_in[8];
    const float* ftb1   = (const float*)d_in[9];
    const float* ftW2   = (const float*)d_in[10];
    const float* ftb2   = (const float*)d_in[11];
    const float* ftW3   = (const float*)d_in[12];
    const float* ftb3   = (const float*)d_in[13];
    const float* W_post = (const float*)d_in[14];
    const float* b_post = (const float*)d_in[15];
    const float* gamma  = (const float*)d_in[16];
    const float* beta   = (const float*)d_in[17];
    float* out = (float*)d_out;

    char* ws = (char*)d_ws;
    size_t off = 0;
    int* rowptr   = (int*)(ws + off); off += align256((NN + 1) * 4);
    int* cursor   = (int*)(ws + off); off += align256(NN * 4);
    int* deg      = (int*)(ws + off); off += align256(NN * 4);
    int* csr_src  = (int*)(ws + off); off += align256((size_t)EE * 4);
    int* csr_eid  = (int*)(ws + off); off += align256((size_t)EE * 4);
    float* csr_wl = (float*)(ws + off); off += align256((size_t)EE * 4);
    float* colsum = (float*)(ws + off); off += 512;
    float* colsq  = (float*)(ws + off); off += 512;
    float* f1v    = (float*)(ws + off); off += align256(NN * 4);
    float* f2v    = (float*)(ws + off); off += align256(NN * 4);
    float* U      = (float*)(ws + off); off += (size_t)NN * 128 * 4;
    float* V      = (float*)(ws + off); off += (size_t)NN * 128 * 4;
    float* agg    = (float*)(ws + off);          // rest of ws (chunk-sized)

    // Adaptive agg chunking: deterministic per run (ws_size constant).
    size_t avail = (ws_size > off) ? ws_size - off : 0;
    const size_t per_node = 640 * 4;
    int chunkN = NN;
    if (avail < (size_t)NN * per_node) {
        chunkN = (int)(avail / per_node);
        chunkN = (chunkN / BM) * BM;
        if (chunkN < BM) chunkN = BM;  // best effort
    }

    hipMemsetAsync(deg, 0, NN * 4, stream);
    hipMemsetAsync(colsum, 0, 1024, stream);   // colsum + colsq contiguous

    k_deg<<<1875, 256, 0, stream>>>(dst, deg);
    k_scan<<<1, 1024, 0, stream>>>(deg, rowptr, cursor);
    k_scatter<<<1875, 256, 0, stream>>>(src, dst, eig, ftW1, ftb1, ftW2, ftb2,
                                        ftW3, ftb3, cursor, csr_src, csr_eid, csr_wl);
    k_pre<<<(NN + 63) / 64, 512, 0, stream>>>(h, W_pre, U, V);

    for (int vb = 0; vb < NN; vb += chunkN) {
        int vcap = (vb + chunkN < NN) ? vb + chunkN : NN;
        int cN = vcap - vb;
        k_agg<<<(cN + 3) / 4, 256, 0, stream>>>(U, V, ef, b_pre, W_pre, csr_src,
                                                rowptr, csr_eid, csr_wl, agg,
                                                f1v, f2v, vb, vcap);
        k_gemm<<<(cN + BM - 1) / BM, 512, 0, stream>>>(h, agg, f1v, f2v, W_post,
                                                       b_post, snorm, out, colsum,
                                                       colsq, vb, vcap);
    }
    k_norm<<<3750, 256, 0, stream>>>(out, colsum, colsq, gamma, beta);
}